// Round 4
// baseline (1052.520 us; speedup 1.0000x reference)
//
#include <hip/hip_runtime.h>
#include <stdint.h>

typedef short short8 __attribute__((ext_vector_type(8)));
typedef float floatx16 __attribute__((ext_vector_type(16)));

#define NPTS 16384
#define TILE_M 64
#define THREADS 1024
#define PA 3   // A-fragment (LDS) prefetch depth
#define PB 4   // B-fragment (global/L2) prefetch depth

__device__ inline unsigned short f2bf(float f) {
  union { float f; unsigned u; } v; v.f = f;
  unsigned u = v.u;
  unsigned r = (u + 0x7fffu + ((u >> 16) & 1u)) >> 16;
  return (unsigned short)r;
}
__device__ inline float bf2f(unsigned short h) {
  union { unsigned u; float f; } v; v.u = ((unsigned)h) << 16;
  return v.f;
}

// Fused dyn(p_eval) for 64 points per WG, 16 waves (4/SIMD for TLP).
// Wave w: M-tile (w&1), N-tiles (w>>1)*2 + {0,1}. 32x32x16 bf16 MFMA,
// B register-prefetched from fragment-major weights (no K-loop barriers,
// W read exactly once per WG per GEMM).
__global__ __launch_bounds__(THREADS, 4) void dyn_kernel(
    const float* __restrict__ p, const float* __restrict__ kprev, float cf,
    const unsigned short* __restrict__ w2f, const unsigned short* __restrict__ w3f,
    const float* __restrict__ sf, const float* __restrict__ w1,
    const float* __restrict__ b1, const float* __restrict__ b2,
    const float* __restrict__ b3, const float* __restrict__ w4,
    const float* __restrict__ b4, int update_mode, float* __restrict__ outp,
    const float* __restrict__ k1v, const float* __restrict__ k2v,
    const float* __restrict__ k3v, float dt6)
{
  // act: 64 x 512 bf16, row pitch 520 u16 (1040 B) -> b128 reads conflict-free
  __shared__ unsigned short act[TILE_M][520];
  __shared__ float pe[TILE_M][3];
  __shared__ float red[192][16];

  const int tid = threadIdx.x;
  const int wg = blockIdx.x;
  const int m0 = wg * TILE_M;
  const int batch = wg >> 6;          // 64 WGs per batch
  const int lane = tid & 63;
  const int wid = tid >> 6;           // 0..15

  // ---- p_eval ----
  if (tid < TILE_M * 3) {
    int gi = m0 * 3 + tid;
    ((float*)pe)[tid] = p[gi] + cf * kprev[gi];
  }
  __syncthreads();

  // ---- phase 1: h = relu(p@W1.T + b1) * sf  (each thread: 1 col, 32 rows) ----
  {
    int j = tid & 511;
    int mh = (tid >> 9) * 32;
    float ww0 = w1[j * 3 + 0], ww1 = w1[j * 3 + 1], ww2 = w1[j * 3 + 2];
    float bb = b1[j];
    float s = sf[batch * 512 + j];
    #pragma unroll 4
    for (int mm = 0; mm < 32; ++mm) {
      int m = mh + mm;
      float v = fmaf(pe[m][0], ww0, fmaf(pe[m][1], ww1, fmaf(pe[m][2], ww2, bb)));
      v = fmaxf(v, 0.f) * s;
      act[m][j] = f2bf(v);
    }
  }
  __syncthreads();

  // ---- phases 2+3: two residual GEMMs, h = relu(h@W.T + b) + h ----
  // A-frag: act[(wid&1)*32 + (lane&31)][kt*16 + (lane>>5)*8 ..+8]
  // B-frag: fragment-major wf[((kt*16 + nt)*64 + lane)*8]
  const int aBase = ((wid & 1) * 32 + (lane & 31)) * 1040 + (lane >> 5) * 16;
  const char* actB = (const char*)&act[0][0];
  const int ntA = (wid >> 1) * 2;
  const int bidx0 = (ntA + 0) * 64 + lane;   // short8 index within a kt slab
  const int bidx1 = (ntA + 1) * 64 + lane;

  for (int s = 0; s < 2; ++s) {
    const short8* bptr = (const short8*)(s ? w3f : w2f);
    const float* bias = s ? b3 : b2;
    floatx16 acc0{}, acc1{};

    short8 aq[PA], bq0[PB], bq1[PB];
    #pragma unroll
    for (int i = 0; i < PB - 1; ++i) {
      bq0[i] = bptr[i * 1024 + bidx0];
      bq1[i] = bptr[i * 1024 + bidx1];
    }
    #pragma unroll
    for (int i = 0; i < PA - 1; ++i)
      aq[i] = *(const short8*)(actB + aBase + i * 32);

    #pragma unroll
    for (int kt = 0; kt < 32; ++kt) {
      int la = kt + PA - 1;
      if (la < 32)
        aq[la % PA] = *(const short8*)(actB + aBase + la * 32);
      int lb = kt + PB - 1;
      if (lb < 32) {
        bq0[lb % PB] = bptr[lb * 1024 + bidx0];
        bq1[lb % PB] = bptr[lb * 1024 + bidx1];
      }
      acc0 = __builtin_amdgcn_mfma_f32_32x32x16_bf16(aq[kt % PA], bq0[kt % PB], acc0, 0, 0, 0);
      acc1 = __builtin_amdgcn_mfma_f32_32x32x16_bf16(aq[kt % PA], bq1[kt % PB], acc1, 0, 0, 0);
    }

    __syncthreads();   // all waves done reading act before epilogue writes
    // epilogue: C/D layout col=lane&31, row=(reg&3)+8*(reg>>2)+4*(lane>>5)
    {
      int col = lane & 31;
      int ncol0 = (ntA + 0) * 32 + col;
      int ncol1 = (ntA + 1) * 32 + col;
      float bs0 = bias[ncol0], bs1 = bias[ncol1];
      int rbase = 4 * (lane >> 5) + (wid & 1) * 32;
      #pragma unroll
      for (int reg = 0; reg < 16; ++reg) {
        int row = (reg & 3) + 8 * (reg >> 2) + rbase;
        float v = fmaxf(acc0[reg] + bs0, 0.f) + bf2f(act[row][ncol0]);
        act[row][ncol0] = f2bf(v);
        v = fmaxf(acc1[reg] + bs1, 0.f) + bf2f(act[row][ncol1]);
        act[row][ncol1] = f2bf(v);
      }
    }
    __syncthreads();
  }

  // ---- phase 4: flow = tanh(h@W4.T + b4)  (16 threads per point) ----
  {
    int m = tid >> 4, jj = tid & 15;
    const unsigned short* arow = &act[m][0];
    float s0 = 0.f, s1 = 0.f, s2 = 0.f;
    #pragma unroll 8
    for (int kk = 0; kk < 32; ++kk) {
      int k = kk * 16 + jj;
      float a = bf2f(arow[k]);
      s0 = fmaf(a, w4[k], s0);
      s1 = fmaf(a, w4[512 + k], s1);
      s2 = fmaf(a, w4[1024 + k], s2);
    }
    red[m * 3 + 0][jj] = s0;
    red[m * 3 + 1][jj] = s1;
    red[m * 3 + 2][jj] = s2;
  }
  __syncthreads();
  if (tid < 192) {
    int mm = tid / 3, cc = tid % 3;
    float ssum = 0.f;
    #pragma unroll
    for (int q = 0; q < 16; ++q) ssum += red[tid][q];
    float flow = tanhf(ssum + b4[cc]);
    int gi = (m0 + mm) * 3 + cc;
    if (update_mode) {
      outp[gi] = p[gi] + dt6 * (k1v[gi] + 2.f * k2v[gi] + 2.f * k3v[gi] + flow);
    } else {
      outp[gi] = flow;
    }
  }
}

// ---- setup: shuffle W (512x512 fp32 row-major, W[n][k]) into fragment-major
// bf16: dst[((kt*16 + nt)*64 + lane)*8 + j] = W[nt*32+(lane&31)][kt*16+(lane>>5)*8+j]
__global__ void setup_shuffle(const float* s0, const float* s1, const float* s2,
                              const float* s3, unsigned short* dst) {
  int idx = blockIdx.x * blockDim.x + threadIdx.x;   // 4 * 32768
  int w = idx >> 15;
  int r = idx & 32767;            // (kt*16+nt)*64 + lane
  int lane = r & 63;
  int tile = r >> 6;
  int nt = tile & 15, kt = tile >> 4;
  const float* W = (w == 0) ? s0 : (w == 1) ? s1 : (w == 2) ? s2 : s3;
  int n = nt * 32 + (lane & 31);
  int k0 = kt * 16 + (lane >> 5) * 8;
  const float* src = W + n * 512 + k0;
  unsigned short* d = dst + ((size_t)w << 18) + (size_t)r * 8;
  #pragma unroll
  for (int j = 0; j < 8; ++j) d[j] = f2bf(src[j]);
}

__global__ void setup_copy(const float* x, float* p) {
  int i = blockIdx.x * blockDim.x + threadIdx.x;
  if (i < NPTS * 3) p[i] = x[i];
}

__global__ void setup_sf(const float* code, const float* cw1, const float* cb1,
                         const float* cw2, const float* cb2, float* sfout) {
  int f = blockIdx.x >> 2, b = blockIdx.x & 3;
  const float* cw = f ? cw2 : cw1;
  const float* cb = f ? cb2 : cb1;
  int j = threadIdx.x;
  const float* c = code + b * 512;
  float s = cb[j];
  for (int k = 0; k < 512; ++k) s = fmaf(c[k], cw[j * 512 + k], s);
  sfout[f * 2048 + b * 512 + j] = tanhf(s);
}

extern "C" void kernel_launch(void* const* d_in, const int* in_sizes, int n_in,
                              void* d_out, int out_size, void* d_ws, size_t ws_size,
                              hipStream_t stream) {
  const float* code = (const float*)d_in[0];
  const float* x    = (const float*)d_in[1];
  char* ws = (char*)d_ws;
  float* p  = (float*)(ws);
  float* k1 = (float*)(ws + 196608);
  float* k2 = (float*)(ws + 2 * 196608);
  float* k3 = (float*)(ws + 3 * 196608);
  float* sf = (float*)(ws + 4 * 196608);
  unsigned short* wbf = (unsigned short*)(ws + 4 * 196608 + 16384);

  setup_shuffle<<<512, 256, 0, stream>>>((const float*)d_in[4], (const float*)d_in[6],
                                         (const float*)d_in[14], (const float*)d_in[16], wbf);
  setup_copy<<<192, 256, 0, stream>>>(x, p);
  setup_sf<<<8, 512, 0, stream>>>(code, (const float*)d_in[10], (const float*)d_in[11],
                                  (const float*)d_in[20], (const float*)d_in[21], sf);

  const float dt = 0.05f, dt6 = dt / 6.0f;
  float* out = (float*)d_out;
  for (int f = 0; f < 2; ++f) {
    const float* w1 = (const float*)d_in[2 + f * 10];
    const float* b1 = (const float*)d_in[3 + f * 10];
    const float* b2 = (const float*)d_in[5 + f * 10];
    const float* b3 = (const float*)d_in[7 + f * 10];
    const float* w4 = (const float*)d_in[8 + f * 10];
    const float* b4 = (const float*)d_in[9 + f * 10];
    const unsigned short* w2b = wbf + (f * 2 + 0) * 262144;
    const unsigned short* w3b = wbf + (f * 2 + 1) * 262144;
    const float* sff = sf + f * 2048;
    for (int st = 0; st < 4; ++st) {
      int last = (f == 1 && st == 3);
      dyn_kernel<<<256, THREADS, 0, stream>>>(p, p,  0.0f,      w2b, w3b, sff, w1, b1, b2, b3, w4, b4,
                                              0, k1, p, p, p, dt6);
      dyn_kernel<<<256, THREADS, 0, stream>>>(p, k1, 0.5f * dt, w2b, w3b, sff, w1, b1, b2, b3, w4, b4,
                                              0, k2, p, p, p, dt6);
      dyn_kernel<<<256, THREADS, 0, stream>>>(p, k2, 0.5f * dt, w2b, w3b, sff, w1, b1, b2, b3, w4, b4,
                                              0, k3, p, p, p, dt6);
      dyn_kernel<<<256, THREADS, 0, stream>>>(p, k3, dt,        w2b, w3b, sff, w1, b1, b2, b3, w4, b4,
                                              1, last ? out : p, k1, k2, k3, dt6);
    }
  }
}